// Round 9
// baseline (275.479 us; speedup 1.0000x reference)
//
#include <hip/hip_runtime.h>
#include <hip/hip_bf16.h>

// NTM cell forward: T=512, B=32, D=1024, N=128. All I/O f32.
// R18: R17's split proved gemm5 <= 66.4us and exposed ~55us of
// inter-dispatch overhead (6 kernels). This round: (1) fuse knorm into
// gemm5's epilogue (block owns all 640 cols of its 64 rows: 16-lane
// shfl partial + 2KB LDS cross-wave reduce; writes kn/wv/q/e, skips
// bn4) -> kills one kernel + ~42MB C roundtrip; (2) B-prefetch depth
// 1->3 in the kk-loop (4-slot static ring) to cover L2 latency.
// Scan: R14-verbatim split (66.4us x2, known-good). 5 kernels total.
// ws: C (41,943,040) | W2 (1,310,720) | S_mid (8,388,608).

typedef __attribute__((ext_vector_type(8))) short bf16x8;
typedef __attribute__((ext_vector_type(4))) float f32x4;
typedef __attribute__((ext_vector_type(2))) float f32x2;
typedef __attribute__((ext_vector_type(4))) unsigned short u16x4;
typedef __attribute__((ext_vector_type(8))) unsigned short u16x8;

static constexpr int T_STEPS = 512;
static constexpr int BATCH   = 32;
static constexpr int DDIM    = 1024;
static constexpr int NDIM    = 128;
static constexpr int LDC     = 5 * NDIM;         // 640
static constexpr int MROWS   = T_STEPS * BATCH;  // 16384
static constexpr int OUT_N   = T_STEPS * BATCH * NDIM;  // 2,097,152

static constexpr size_t C_BYTES  = (size_t)MROWS * LDC * 4;   // 41,943,040
static constexpr size_t W2_BYTES = 5ull * NDIM * DDIM * 2;    // 1,310,720

// round-to-nearest-even f32 -> bf16
__device__ __forceinline__ unsigned short rne_bf16(float v) {
    unsigned u = __builtin_bit_cast(unsigned, v);
    u += 0x7FFFu + ((u >> 16) & 1u);
    return (unsigned short)(u >> 16);
}

// ---------------- Phase 0: W f32 -> frag-swizzled bf16 ----------------
__global__ __launch_bounds__(256) void wconv_kernel(
    const float* __restrict__ w0, const float* __restrict__ w1,
    const float* __restrict__ w2, const float* __restrict__ w3,
    const float* __restrict__ w4,
    unsigned short* __restrict__ W2)
{
    const int idx = blockIdx.x * 256 + threadIdx.x;   // f32x4 index, 163840 total
    const size_t e = (size_t)idx * 4;
    const int bn = (int)(e >> 17);                    // 131,072 elems per weight
    const int r  = (int)(e & 131071);
    const int n  = r >> 10;
    const int k  = r & 1023;

    const float* wp = w0;
    if (bn == 1) wp = w1;
    else if (bn == 2) wp = w2;
    else if (bn == 3) wp = w3;
    else if (bn == 4) wp = w4;

    f32x4 v = *(const f32x4*)(wp + r);
    u16x4 h;
#pragma unroll
    for (int j = 0; j < 4; ++j) h[j] = rne_bf16(v[j]);

    const int kk   = k >> 5;
    const int quad = (k >> 3) & 3;
    const size_t off = ((((size_t)(bn * 32 + kk) * 128 + n) * 4 + quad) * 8) + (k & 7);
    *(u16x4*)(W2 + off) = h;
}

// ---------------- Phase 1: A-resident GEMM, fused knorm epilogue ------------
// kk-loop with B-prefetch distance 3 (4-slot static ring) and A distance 1.
template<int NB>
__device__ __forceinline__ void run_pass(
    const unsigned short* __restrict__ ldsb,
    const unsigned short* const (&bpp)[NB],
    int l16, int quad, int aswz,
    f32x4 (&acc)[NB][4])
{
    auto LDA = [&](int mi, int kk) -> bf16x8 {
        if (kk > 31) kk = 31;
        const int byteo = (mi * 16 + l16) * 2048 + ((kk * 64 + quad * 16) ^ aswz);
        return *(const bf16x8*)((const char*)ldsb + byteo);
    };
    auto LDB = [&](int q, int kk) -> bf16x8 {
        if (kk > 31) kk = 31;
        return *(const bf16x8*)(bpp[q] + (size_t)kk * 4096);
    };

#pragma unroll
    for (int q = 0; q < NB; ++q)
#pragma unroll
        for (int mi = 0; mi < 4; ++mi) acc[q][mi] = (f32x4)(0.0f);

    bf16x8 a0[4], a1[4], b0[NB], b1[NB], b2[NB], b3[NB];
#pragma unroll
    for (int mi = 0; mi < 4; ++mi) a0[mi] = LDA(mi, 0);
#pragma unroll
    for (int q = 0; q < NB; ++q) {
        b0[q] = LDB(q, 0); b1[q] = LDB(q, 1);
        b2[q] = LDB(q, 2); b3[q] = LDB(q, 3);
    }

    for (int kk = 0; kk < 32; kk += 4) {
        // phase 0: compute kk
#pragma unroll
        for (int mi = 0; mi < 4; ++mi) a1[mi] = LDA(mi, kk + 1);
#pragma unroll
        for (int q = 0; q < NB; ++q)
#pragma unroll
            for (int mi = 0; mi < 4; ++mi)
                acc[q][mi] = __builtin_amdgcn_mfma_f32_16x16x32_bf16(
                    a0[mi], b0[q], acc[q][mi], 0, 0, 0);
#pragma unroll
        for (int q = 0; q < NB; ++q) b0[q] = LDB(q, kk + 4);
        // phase 1: compute kk+1
#pragma unroll
        for (int mi = 0; mi < 4; ++mi) a0[mi] = LDA(mi, kk + 2);
#pragma unroll
        for (int q = 0; q < NB; ++q)
#pragma unroll
            for (int mi = 0; mi < 4; ++mi)
                acc[q][mi] = __builtin_amdgcn_mfma_f32_16x16x32_bf16(
                    a1[mi], b1[q], acc[q][mi], 0, 0, 0);
#pragma unroll
        for (int q = 0; q < NB; ++q) b1[q] = LDB(q, kk + 5);
        // phase 2: compute kk+2
#pragma unroll
        for (int mi = 0; mi < 4; ++mi) a1[mi] = LDA(mi, kk + 3);
#pragma unroll
        for (int q = 0; q < NB; ++q)
#pragma unroll
            for (int mi = 0; mi < 4; ++mi)
                acc[q][mi] = __builtin_amdgcn_mfma_f32_16x16x32_bf16(
                    a0[mi], b2[q], acc[q][mi], 0, 0, 0);
#pragma unroll
        for (int q = 0; q < NB; ++q) b2[q] = LDB(q, kk + 6);
        // phase 3: compute kk+3
#pragma unroll
        for (int mi = 0; mi < 4; ++mi) a0[mi] = LDA(mi, kk + 4);
#pragma unroll
        for (int q = 0; q < NB; ++q)
#pragma unroll
            for (int mi = 0; mi < 4; ++mi)
                acc[q][mi] = __builtin_amdgcn_mfma_f32_16x16x32_bf16(
                    a1[mi], b3[q], acc[q][mi], 0, 0, 0);
#pragma unroll
        for (int q = 0; q < NB; ++q) b3[q] = LDB(q, kk + 7);
    }
}

// 256 blocks, 512 threads (8 waves), 1 block/CU (130 KiB LDS).
__global__ __launch_bounds__(512, 2) void gemm6_kernel(
    const float* __restrict__ x,
    const unsigned short* __restrict__ W2,
    float* __restrict__ C)
{
    __shared__ unsigned short lds[64 * 1024 + 1024];  // A tile (128K) + reduce (2K)

    const int m0   = blockIdx.x * 64;
    const int tid  = threadIdx.x;
    const int wave = tid >> 6, lane = tid & 63;
    const int quad = lane >> 4, l16 = lane & 15;

    // ---- stage: coalesced 32 B/thread/iter, swizzled 16 B LDS writes ----
    {
        const int k8 = tid & 127;       // 8-elem k-group 0..127
        const int rb = tid >> 7;        // 0..3
#pragma unroll 4
        for (int it = 0; it < 16; ++it) {
            const int row = it * 4 + rb;
            const float* src = x + (size_t)(m0 + row) * DDIM + k8 * 8;
            f32x4 v0 = *(const f32x4*)src;
            f32x4 v1 = *(const f32x4*)(src + 4);
            u16x8 h;
            h[0] = rne_bf16(v0[0]); h[1] = rne_bf16(v0[1]);
            h[2] = rne_bf16(v0[2]); h[3] = rne_bf16(v0[3]);
            h[4] = rne_bf16(v1[0]); h[5] = rne_bf16(v1[1]);
            h[6] = rne_bf16(v1[2]); h[7] = rne_bf16(v1[3]);
            const int byteo = row * 2048 + ((k8 * 16) ^ ((row & 7) << 4));
            *(u16x8*)((char*)lds + byteo) = h;
        }
    }
    __syncthreads();

    const int aswz = (l16 & 7) << 4;
    const unsigned short* bp = W2 + ((size_t)((wave * 16 + l16) * 4 + quad)) * 8;
    float* lds2f = (float*)((char*)lds + 131072);  // [row 0..63][wave 0..7]

    auto STORE = [&](int bn, const f32x4 (&a)[4]) {
#pragma unroll
        for (int mi = 0; mi < 4; ++mi) {
            const int rw = m0 + mi * 16 + quad * 4;
            const int cl = bn * 128 + wave * 16 + l16;
#pragma unroll
            for (int r = 0; r < 4; ++r)
                C[(size_t)(rw + r) * LDC + cl] = a[mi][r];
        }
    };

    // ---- pass 1: v (bn1) & w (bn4) -> wv ----
    f32x4 wv[4];
    {
        const unsigned short* bppVW[2] = { bp + 1 * 131072, bp + 4 * 131072 };
        f32x4 acc[2][4];
        run_pass<2>(lds, bppVW, l16, quad, aswz, acc);
#pragma unroll
        for (int mi = 0; mi < 4; ++mi)
#pragma unroll
            for (int r = 0; r < 4; ++r)
                wv[mi][r] = acc[0][mi][r] * acc[1][mi][r];
    }

    // ---- pass 2: k (bn0) & q (bn2); fused row-norm on k ----
    {
        const unsigned short* bppKQ[2] = { bp, bp + 2 * 131072 };
        f32x4 acc[2][4];
        run_pass<2>(lds, bppKQ, l16, quad, aswz, acc);

        // per-(mi,r) partial: sum of k^2 over this wave's 16 cols
#pragma unroll
        for (int mi = 0; mi < 4; ++mi)
#pragma unroll
            for (int r = 0; r < 4; ++r) {
                float s = acc[0][mi][r] * acc[0][mi][r];
                s += __shfl_xor(s, 1);
                s += __shfl_xor(s, 2);
                s += __shfl_xor(s, 4);
                s += __shfl_xor(s, 8);
                if (l16 == 0)
                    lds2f[(mi * 16 + quad * 4 + r) * 8 + wave] = s;
            }
        __syncthreads();

        // total over 8 waves, then scale k rows
#pragma unroll
        for (int mi = 0; mi < 4; ++mi)
#pragma unroll
            for (int r = 0; r < 4; ++r) {
                const int row = mi * 16 + quad * 4 + r;
                f32x4 p0 = *(const f32x4*)&lds2f[row * 8];
                f32x4 p1 = *(const f32x4*)&lds2f[row * 8 + 4];
                float ss = (p0[0] + p0[1]) + (p0[2] + p0[3])
                         + (p1[0] + p1[1]) + (p1[2] + p1[3]);
                float inv = __builtin_amdgcn_rcpf(sqrtf(ss) + 1e-6f);
                acc[0][mi][r] *= inv;
            }

        STORE(0, acc[0]);  // kn
        STORE(1, wv);      // w*v
        STORE(2, acc[1]);  // q
    }

    // ---- pass 3: e (bn3) ----
    {
        const unsigned short* bppE[1] = { bp + 3 * 131072 };
        f32x4 acc[1][4];
        run_pass<1>(lds, bppE, l16, quad, aswz, acc);
        STORE(3, acc[0]);  // e  (bn4 never written; nothing reads it)
    }
}

// ---------------- recurrent scan ----------------
__device__ __forceinline__ float tanh_fast(float xx) {
    float ex = __builtin_amdgcn_exp2f(xx * 2.8853900817779268f);  // e^(2x)
    float r  = __builtin_amdgcn_rcpf(ex + 1.0f);
    return fmaf(-2.0f, r, 1.0f);
}

template <int CTRL, int RMASK>
__device__ __forceinline__ float dpp_add(float x) {
    int yi = __builtin_amdgcn_update_dpp(
        0, __builtin_bit_cast(int, x), CTRL, RMASK, 0xF, true);
    return x + __builtin_bit_cast(float, yi);
}

// Sum across each 32-lane group; valid in lanes 16..31 / 48..63.
__device__ __forceinline__ float dpp_reduce32(float x) {
    x = dpp_add<0xB1,  0xF>(x);  // + lane^1
    x = dpp_add<0x4E,  0xF>(x);  // + lane^2
    x = dpp_add<0x141, 0xF>(x);  // row_half_mirror: + lane^4
    x = dpp_add<0x140, 0xF>(x);  // row_mirror: + lane^8
    x = dpp_add<0x142, 0xA>(x);  // row_bcast15: rows 1,3 += row 0,2 sum
    return x;
}

// Half-sequence scan (R14-verbatim body). NOUTER unrolled-4 outer iters
// from t0; Sin -> Sout; TAIL adds the clamped peeled last iteration.
template<int NOUTER, bool TAIL>
__global__ __launch_bounds__(256, 2) void ntm_scan_part(
    const float* __restrict__ C, const float* __restrict__ Sin,
    float* __restrict__ Sout, float* __restrict__ out, int t0)
{
    const int L    = blockIdx.x;            // 0..511
    const int b    = (L & 7) + 8 * ((L >> 3) & 3);
    const int row  = (L >> 5) * 8 + (threadIdx.x >> 5);
    const int g    = threadIdx.x & 31;
    const int col0 = g * 4;

    f32x4 S = *(const f32x4*)(Sin + ((size_t)b * NDIM + row) * NDIM + col0);

    const size_t STRIDE = (size_t)BATCH * LDC;
    const float* pb = C + (size_t)b * LDC;
    const float* p0 = pb + (size_t)t0 * STRIDE;

    f32x4 kS[4], qS[4];
    float eS[4], wvS[4];

#pragma unroll
    for (int s = 0; s < 2; ++s) {
        const float* p = p0 + (size_t)s * STRIDE;
        kS[s]  = *(const f32x4*)(p + col0);
        qS[s]  = *(const f32x4*)(p + 2 * NDIM + col0);
        eS[s]  = p[3 * NDIM + row];
        wvS[s] = p[NDIM + row];
    }

    float* opc = out + (size_t)t0 * BATCH * NDIM + (size_t)b * NDIM + row;
    const float* pc = p0 + 2 * STRIDE;           // prefetch cursor (t+2)

    for (int ti = 0; ti < NOUTER; ++ti) {
#pragma unroll
        for (int j = 0; j < 4; ++j) {
            const int ps = (j + 2) & 3;
            kS[ps]  = *(const f32x4*)(pc + col0);
            qS[ps]  = *(const f32x4*)(pc + 2 * NDIM + col0);
            eS[ps]  = pc[3 * NDIM + row];
            wvS[ps] = pc[NDIM + row];
            pc += STRIDE;

            float dot = 0.0f;
#pragma unroll
            for (int u = 0; u < 4; ++u) {
                float t0v = fmaf(-eS[j], S[u], wvS[j]);
                float pre = fmaf(kS[j][u], t0v, S[u]);
                S[u] = tanh_fast(pre);
                dot = fmaf(S[u], qS[j][u], dot);
            }
            dot = dpp_reduce32(dot);

            if ((threadIdx.x & 31) == 31)
                *opc = dot;  // raw; silu in epilogue
            opc += BATCH * NDIM;
        }
    }

    if (TAIL) {
#pragma unroll
        for (int j = 0; j < 4; ++j) {
            const int ps = (j + 2) & 3;
            int tp = t0 + NOUTER * 4 + 2 + j;
            if (tp > T_STEPS - 1) tp = T_STEPS - 1;
            const float* p = pb + (size_t)tp * STRIDE;
            kS[ps]  = *(const f32x4*)(p + col0);
            qS[ps]  = *(const f32x4*)(p + 2 * NDIM + col0);
            eS[ps]  = p[3 * NDIM + row];
            wvS[ps] = p[NDIM + row];

            float dot = 0.0f;
#pragma unroll
            for (int u = 0; u < 4; ++u) {
                float t0v = fmaf(-eS[j], S[u], wvS[j]);
                float pre = fmaf(kS[j][u], t0v, S[u]);
                S[u] = tanh_fast(pre);
                dot = fmaf(S[u], qS[j][u], dot);
            }
            dot = dpp_reduce32(dot);

            if ((threadIdx.x & 31) == 31)
                *opc = dot;
            opc += BATCH * NDIM;
        }
    }

    *(f32x4*)(Sout + ((size_t)b * NDIM + row) * NDIM + col0) = S;
}

// ---------------- silu epilogue: y = d^2 * sigmoid(d) over out[0:OUT_N] ----
__global__ __launch_bounds__(256) void silu_kernel(float* __restrict__ out)
{
    const int i = blockIdx.x * 256 + threadIdx.x;  // f32x4 index
    f32x4 d = ((const f32x4*)out)[i];
    f32x4 y;
#pragma unroll
    for (int j = 0; j < 4; ++j) {
        float sg = __builtin_amdgcn_rcpf(
            1.0f + __builtin_amdgcn_exp2f(-d[j] * 1.4426950408889634f));
        y[j] = d[j] * d[j] * sg;
    }
    ((f32x4*)out)[i] = y;
}

extern "C" void kernel_launch(void* const* d_in, const int* in_sizes, int n_in,
                              void* d_out, int out_size, void* d_ws, size_t ws_size,
                              hipStream_t stream) {
    const float* x  = (const float*)d_in[0];
    const float* S0 = (const float*)d_in[1];
    const float* wk = (const float*)d_in[2];
    const float* wv = (const float*)d_in[3];
    const float* wq = (const float*)d_in[4];
    const float* we = (const float*)d_in[5];
    const float* ww = (const float*)d_in[6];
    float* out = (float*)d_out;
    float* C   = (float*)d_ws;
    unsigned short* W2 = (unsigned short*)((char*)d_ws + C_BYTES);
    float* S_mid = (float*)((char*)d_ws + C_BYTES + W2_BYTES);

    wconv_kernel<<<640, 256, 0, stream>>>(wk, wv, wq, we, ww, W2);
    gemm6_kernel<<<256, 512, 0, stream>>>(x, W2, C);
    // t 0..255 (prefetch reaches t=257, valid), S0 -> S_mid
    ntm_scan_part<64, false><<<512, 256, 0, stream>>>(C, S0, S_mid, out, 0);
    // t 256..507 main + 508..511 clamped tail, S_mid -> final S in out
    ntm_scan_part<63, true><<<512, 256, 0, stream>>>(
        C, S_mid, out + (size_t)OUT_N, out, 256);
    silu_kernel<<<OUT_N / 1024, 256, 0, stream>>>(out);
}